// Round 1
// baseline (288.800 us; speedup 1.0000x reference)
//
#include <hip/hip_runtime.h>
#include <hip/hip_bf16.h>

#define D 1024            // embedding dim (reference hard-codes 1024)
#define EPS 1e-8f
#define WEIGHT 0.01f

// One wave (64 lanes) per pair. 4 waves per 256-thread block.
// Each lane reads 4 float4 (16 floats) from each of the two rows -> 1024 floats/row.
__global__ void __launch_bounds__(256)
semantic_anchor_loss_kernel(const float* __restrict__ W,
                            const int* __restrict__ idx_a,
                            const int* __restrict__ idx_m,
                            float* __restrict__ out,
                            int n_pairs, float scale) {
    const int wave = threadIdx.x >> 6;            // 0..3
    const int lane = threadIdx.x & 63;
    const int pair = blockIdx.x * 4 + wave;
    if (pair >= n_pairs) return;

    const float4* __restrict__ a =
        (const float4*)(W + (size_t)idx_a[pair] * D);
    const float4* __restrict__ m =
        (const float4*)(W + (size_t)idx_m[pair] * D);

    float dot = 0.f, na2 = 0.f, nm2 = 0.f;
#pragma unroll
    for (int i = 0; i < 4; ++i) {
        const float4 av = a[lane + 64 * i];
        const float4 mv = m[lane + 64 * i];
        dot += av.x * mv.x + av.y * mv.y + av.z * mv.z + av.w * mv.w;
        na2 += av.x * av.x + av.y * av.y + av.z * av.z + av.w * av.w;
        nm2 += mv.x * mv.x + mv.y * mv.y + mv.z * mv.z + mv.w * mv.w;
    }

    // wave-64 butterfly reduction
#pragma unroll
    for (int off = 32; off > 0; off >>= 1) {
        dot += __shfl_down(dot, off, 64);
        na2 += __shfl_down(na2, off, 64);
        nm2 += __shfl_down(nm2, off, 64);
    }

    if (lane == 0) {
        const float na = fmaxf(sqrtf(na2), EPS);
        const float nm = fmaxf(sqrtf(nm2), EPS);
        const float sim = dot / (na * nm);
        atomicAdd(out, (1.0f - sim) * scale);   // scale = WEIGHT / n_pairs
    }
}

extern "C" void kernel_launch(void* const* d_in, const int* in_sizes, int n_in,
                              void* d_out, int out_size, void* d_ws, size_t ws_size,
                              hipStream_t stream) {
    const float* W     = (const float*)d_in[0];
    const int*   idx_a = (const int*)d_in[1];
    const int*   idx_m = (const int*)d_in[2];
    float*       out   = (float*)d_out;
    const int n_pairs  = in_sizes[1];

    // d_out is poisoned 0xAA before every timed call -> zero it on-stream.
    hipMemsetAsync(d_out, 0, sizeof(float), stream);

    const float scale = WEIGHT / (float)n_pairs;
    const int blocks = (n_pairs + 3) / 4;        // 4 pairs (waves) per block
    semantic_anchor_loss_kernel<<<blocks, 256, 0, stream>>>(
        W, idx_a, idx_m, out, n_pairs, scale);
}

// Round 2
// 246.774 us; speedup vs baseline: 1.1703x; 1.1703x over previous
//
#include <hip/hip_runtime.h>
#include <hip/hip_bf16.h>

#define D 1024            // embedding dim (reference hard-codes 1024)
#define EPS 1e-8f
#define WEIGHT 0.01f

// Stage 1: one wave (64 lanes) per pair, 4 waves per 256-thread block.
// Each lane reads 4 float4 (16 floats) from each row -> 1024 floats/row.
// Writes per-pair (1 - sim) to ws[pair]; NO same-address atomics.
__global__ void __launch_bounds__(256)
pair_loss_kernel(const float* __restrict__ W,
                 const int* __restrict__ idx_a,
                 const int* __restrict__ idx_m,
                 float* __restrict__ partial,
                 int n_pairs) {
    const int wave = threadIdx.x >> 6;            // 0..3
    const int lane = threadIdx.x & 63;
    const int pair = blockIdx.x * 4 + wave;
    if (pair >= n_pairs) return;

    const float4* __restrict__ a =
        (const float4*)(W + (size_t)idx_a[pair] * D);
    const float4* __restrict__ m =
        (const float4*)(W + (size_t)idx_m[pair] * D);

    float dot = 0.f, na2 = 0.f, nm2 = 0.f;
#pragma unroll
    for (int i = 0; i < 4; ++i) {
        const float4 av = a[lane + 64 * i];
        const float4 mv = m[lane + 64 * i];
        dot += av.x * mv.x + av.y * mv.y + av.z * mv.z + av.w * mv.w;
        na2 += av.x * av.x + av.y * av.y + av.z * av.z + av.w * av.w;
        nm2 += mv.x * mv.x + mv.y * mv.y + mv.z * mv.z + mv.w * mv.w;
    }

#pragma unroll
    for (int off = 32; off > 0; off >>= 1) {
        dot += __shfl_down(dot, off, 64);
        na2 += __shfl_down(na2, off, 64);
        nm2 += __shfl_down(nm2, off, 64);
    }

    if (lane == 0) {
        const float na = fmaxf(sqrtf(na2), EPS);
        const float nm = fmaxf(sqrtf(nm2), EPS);
        partial[pair] = 1.0f - dot / (na * nm);
    }
}

// Stage 2: single 256-thread block reduces n partial values -> scaled scalar.
__global__ void __launch_bounds__(256)
reduce_kernel(const float* __restrict__ partial,
              float* __restrict__ out,
              int n, float scale) {
    __shared__ float sdata[4];
    float s = 0.f;
    for (int i = threadIdx.x; i < n; i += 256) s += partial[i];
#pragma unroll
    for (int off = 32; off > 0; off >>= 1) s += __shfl_down(s, off, 64);
    const int lane = threadIdx.x & 63;
    const int wave = threadIdx.x >> 6;
    if (lane == 0) sdata[wave] = s;
    __syncthreads();
    if (threadIdx.x == 0)
        out[0] = (sdata[0] + sdata[1] + sdata[2] + sdata[3]) * scale;
}

extern "C" void kernel_launch(void* const* d_in, const int* in_sizes, int n_in,
                              void* d_out, int out_size, void* d_ws, size_t ws_size,
                              hipStream_t stream) {
    const float* W     = (const float*)d_in[0];
    const int*   idx_a = (const int*)d_in[1];
    const int*   idx_m = (const int*)d_in[2];
    float*       out   = (float*)d_out;
    float*       part  = (float*)d_ws;            // n_pairs floats of scratch
    const int n_pairs  = in_sizes[1];

    const int blocks = (n_pairs + 3) / 4;         // 4 pairs (waves) per block
    pair_loss_kernel<<<blocks, 256, 0, stream>>>(W, idx_a, idx_m, part, n_pairs);

    const float scale = WEIGHT / (float)n_pairs;
    reduce_kernel<<<1, 256, 0, stream>>>(part, out, n_pairs, scale);
}

// Round 3
// 243.967 us; speedup vs baseline: 1.1838x; 1.0115x over previous
//
#include <hip/hip_runtime.h>
#include <hip/hip_bf16.h>

#define D 1024            // embedding dim (reference hard-codes 1024)
#define EPS 1e-8f
#define WEIGHT 0.01f

// Stage 1: one wave (64 lanes) per pair, 4 waves per 256-thread block.
// Each lane reads 4 float4 (16 floats) from each row -> 1024 floats/row.
// Writes per-pair (1 - sim) to ws[pair]; no same-address atomics.
__global__ void __launch_bounds__(256)
pair_loss_kernel(const float* __restrict__ W,
                 const int* __restrict__ idx_a,
                 const int* __restrict__ idx_m,
                 float* __restrict__ partial,
                 int n_pairs) {
    const int wave = threadIdx.x >> 6;            // 0..3
    const int lane = threadIdx.x & 63;
    const int pair = blockIdx.x * 4 + wave;
    if (pair >= n_pairs) return;

    const float4* __restrict__ a =
        (const float4*)(W + (size_t)idx_a[pair] * D);
    const float4* __restrict__ m =
        (const float4*)(W + (size_t)idx_m[pair] * D);

    float dot = 0.f, na2 = 0.f, nm2 = 0.f;
#pragma unroll
    for (int i = 0; i < 4; ++i) {
        const float4 av = a[lane + 64 * i];
        const float4 mv = m[lane + 64 * i];
        dot += av.x * mv.x + av.y * mv.y + av.z * mv.z + av.w * mv.w;
        na2 += av.x * av.x + av.y * av.y + av.z * av.z + av.w * av.w;
        nm2 += mv.x * mv.x + mv.y * mv.y + mv.z * mv.z + mv.w * mv.w;
    }

#pragma unroll
    for (int off = 32; off > 0; off >>= 1) {
        dot += __shfl_down(dot, off, 64);
        na2 += __shfl_down(na2, off, 64);
        nm2 += __shfl_down(nm2, off, 64);
    }

    if (lane == 0) {
        const float na = fmaxf(sqrtf(na2), EPS);
        const float nm = fmaxf(sqrtf(nm2), EPS);
        partial[pair] = 1.0f - dot / (na * nm);
    }
}

// Stage 2: one 1024-thread block. Each thread loads one float4 (4096 floats
// total in a single parallel memory round-trip), then 16-wave LDS combine.
__global__ void __launch_bounds__(1024)
reduce_kernel(const float* __restrict__ partial,
              float* __restrict__ out,
              int n, float scale) {
    __shared__ float sdata[16];
    const int tid = threadIdx.x;

    float s = 0.f;
    const float4* p4 = (const float4*)partial;
    const int n4 = n >> 2;                        // n is a multiple of 4 here
    for (int i = tid; i < n4; i += 1024) {
        const float4 v = p4[i];
        s += v.x + v.y + v.z + v.w;
    }
    // tail (defensive; n_pairs=4096 has none)
    for (int i = (n4 << 2) + tid; i < n; i += 1024) s += partial[i];

#pragma unroll
    for (int off = 32; off > 0; off >>= 1) s += __shfl_down(s, off, 64);

    const int lane = tid & 63;
    const int wave = tid >> 6;                    // 0..15
    if (lane == 0) sdata[wave] = s;
    __syncthreads();

    if (tid == 0) {
        float t = 0.f;
#pragma unroll
        for (int w = 0; w < 16; ++w) t += sdata[w];
        out[0] = t * scale;
    }
}

extern "C" void kernel_launch(void* const* d_in, const int* in_sizes, int n_in,
                              void* d_out, int out_size, void* d_ws, size_t ws_size,
                              hipStream_t stream) {
    const float* W     = (const float*)d_in[0];
    const int*   idx_a = (const int*)d_in[1];
    const int*   idx_m = (const int*)d_in[2];
    float*       out   = (float*)d_out;
    float*       part  = (float*)d_ws;            // n_pairs floats of scratch
    const int n_pairs  = in_sizes[1];

    const int blocks = (n_pairs + 3) / 4;         // 4 pairs (waves) per block
    pair_loss_kernel<<<blocks, 256, 0, stream>>>(W, idx_a, idx_m, part, n_pairs);

    const float scale = WEIGHT / (float)n_pairs;
    reduce_kernel<<<1, 1024, 0, stream>>>(part, out, n_pairs, scale);
}